// Round 1
// baseline (1070.929 us; speedup 1.0000x reference)
//
#include <hip/hip_runtime.h>
#include <hip/hip_bf16.h>

#define V_NODES 10000
#define E_EDGES 160000
#define H 256
#define LN_EPS 1e-5f

using bf16x8 = __attribute__((ext_vector_type(8))) __bf16;
using f32x4  = __attribute__((ext_vector_type(4))) float;
typedef unsigned short u16;
typedef unsigned int u32;

// LDS leading-dim pad: 48 u16 = 96 B stride (16B-aligned, breaks 8-way bank aliasing)
#define APAD 48

__device__ __forceinline__ u16 f2b(float f) {
    u32 u = __float_as_uint(f);
    u32 r = u + 0x7fffu + ((u >> 16) & 1u);   // RNE
    return (u16)(r >> 16);
}
__device__ __forceinline__ float b2f(u16 h) {
    return __uint_as_float(((u32)h) << 16);
}

// ---------------------------------------------------------------- convert
__global__ __launch_bounds__(256) void convert_kernel(
    const float* __restrict__ h, const float* __restrict__ Wu,
    const float* __restrict__ Wv, const float* __restrict__ Wa,
    const float* __restrict__ Wb, const float* __restrict__ Wc,
    u16* __restrict__ h_b, u16* __restrict__ W4b, u16* __restrict__ Wcb)
{
    int i = blockIdx.x * 256 + threadIdx.x;
    const int NH = V_NODES * H;        // 2,560,000
    const int NW4 = 4 * H * H;         // 262,144
    const int NWC = H * H;             // 65,536
    if (i < NH) {
        h_b[i] = f2b(h[i]);
    } else if (i < NH + NW4) {
        int j = i - NH;
        int w = j >> 16;               // which weight matrix
        int r = j & 0xffff;            // flat index within it
        const float* W = (w == 0) ? Wu : (w == 1) ? Wv : (w == 2) ? Wa : Wb;
        W4b[j] = f2b(W[r]);
    } else if (i < NH + NW4 + NWC) {
        int j = i - NH - NW4;
        Wcb[j] = f2b(Wc[j]);
    }
}

// ---------------------------------------------------------------- node GEMM
// out(V x 1024) = h_b(V x 256) @ W4b(1024 x 256)^T ; col blocks: Uh|Vh|Ah|Bh
__global__ __launch_bounds__(256) void node_gemm(
    const u16* __restrict__ Xb, const u16* __restrict__ Wb,
    const float* __restrict__ bu, const float* __restrict__ bv,
    const float* __restrict__ ba, const float* __restrict__ bb,
    float* __restrict__ Uh, u16* __restrict__ Vh,
    u16* __restrict__ Ah, u16* __restrict__ Bh, int M)
{
    __shared__ __align__(16) u16 As[64][APAD];
    __shared__ __align__(16) u16 Bs[256][APAD];

    int cb_blk = blockIdx.y;
    int row0 = blockIdx.x * 64;
    int tid = threadIdx.x;
    int wave = tid >> 6, lane = tid & 63;
    int quad = lane >> 4, m16 = lane & 15;

    f32x4 acc[4][4];
    for (int a = 0; a < 4; a++)
        for (int b = 0; b < 4; b++)
            acc[a][b] = f32x4{0.f, 0.f, 0.f, 0.f};

    for (int kc = 0; kc < H; kc += 32) {
        { // stage A: 64 rows x 32 k (bf16), 16B per thread
            int r = tid >> 2, seg = tid & 3;
            int gr = row0 + r; if (gr >= M) gr = M - 1;
            *reinterpret_cast<uint4*>(&As[r][seg * 8]) =
                *reinterpret_cast<const uint4*>(&Xb[(size_t)gr * H + kc + seg * 8]);
        }
        { // stage B: 256 W-rows x 32 k, 64B per thread
            const uint4* sp = reinterpret_cast<const uint4*>(
                &Wb[(size_t)(cb_blk * 256 + tid) * H + kc]);
            uint4* dp = reinterpret_cast<uint4*>(&Bs[tid][0]);
            dp[0] = sp[0]; dp[1] = sp[1]; dp[2] = sp[2]; dp[3] = sp[3];
        }
        __syncthreads();
        bf16x8 a[4], b[4];
        for (int rb = 0; rb < 4; rb++)
            a[rb] = *reinterpret_cast<const bf16x8*>(&As[rb * 16 + m16][quad * 8]);
        for (int cb = 0; cb < 4; cb++)
            b[cb] = *reinterpret_cast<const bf16x8*>(&Bs[wave * 64 + cb * 16 + m16][quad * 8]);
        for (int rb = 0; rb < 4; rb++)
            for (int cb = 0; cb < 4; cb++)
                acc[rb][cb] = __builtin_amdgcn_mfma_f32_16x16x32_bf16(
                    a[rb], b[cb], acc[rb][cb], 0, 0, 0);
        __syncthreads();
    }

    const float* bias = (cb_blk == 0) ? bu : (cb_blk == 1) ? bv : (cb_blk == 2) ? ba : bb;
    for (int rb = 0; rb < 4; rb++) {
        for (int cb = 0; cb < 4; cb++) {
            int col = wave * 64 + cb * 16 + m16;
            float bval = bias[col];
            for (int reg = 0; reg < 4; reg++) {
                int r = row0 + rb * 16 + quad * 4 + reg;
                if (r < M) {
                    float v = acc[rb][cb][reg] + bval;
                    size_t idx = (size_t)r * H + col;
                    if (cb_blk == 0)      Uh[idx] = v;
                    else if (cb_blk == 1) Vh[idx] = f2b(v);
                    else if (cb_blk == 2) Ah[idx] = f2b(v);
                    else                  Bh[idx] = f2b(v);
                }
            }
        }
    }
}

// ---------------------------------------------------------------- edge GEMM
// e_new(E x 256) = e @ Wc^T + bc + Ah[dst] + Bh[src], fp32 into d_out e-region
__global__ __launch_bounds__(256) void edge_gemm(
    const float* __restrict__ e, const u16* __restrict__ Wcb,
    const float* __restrict__ bc,
    const u16* __restrict__ Ahb, const u16* __restrict__ Bhb,
    const int* __restrict__ ei,
    float* __restrict__ e_new)
{
    __shared__ __align__(16) u16 As[64][APAD];
    __shared__ __align__(16) u16 Bs[256][APAD];
    __shared__ int s_edge[64], d_edge[64];

    int row0 = blockIdx.x * 64;
    int tid = threadIdx.x;
    int wave = tid >> 6, lane = tid & 63;
    int quad = lane >> 4, m16 = lane & 15;

    if (tid < 64) {
        s_edge[tid] = ei[row0 + tid];
        d_edge[tid] = ei[E_EDGES + row0 + tid];
    }

    f32x4 acc[4][4];
    for (int a = 0; a < 4; a++)
        for (int b = 0; b < 4; b++)
            acc[a][b] = f32x4{0.f, 0.f, 0.f, 0.f};

    for (int kc = 0; kc < H; kc += 32) {
        { // stage A: read e fp32, convert to bf16 inline
            int r = tid >> 2, seg = tid & 3;
            const float4* sp = reinterpret_cast<const float4*>(
                &e[(size_t)(row0 + r) * H + kc + seg * 8]);
            float4 f0 = sp[0], f1 = sp[1];
            ushort4 lo, hi;
            lo.x = f2b(f0.x); lo.y = f2b(f0.y); lo.z = f2b(f0.z); lo.w = f2b(f0.w);
            hi.x = f2b(f1.x); hi.y = f2b(f1.y); hi.z = f2b(f1.z); hi.w = f2b(f1.w);
            *reinterpret_cast<ushort4*>(&As[r][seg * 8])     = lo;
            *reinterpret_cast<ushort4*>(&As[r][seg * 8 + 4]) = hi;
        }
        { // stage B (Wc is 256x256)
            const uint4* sp = reinterpret_cast<const uint4*>(&Wcb[(size_t)tid * H + kc]);
            uint4* dp = reinterpret_cast<uint4*>(&Bs[tid][0]);
            dp[0] = sp[0]; dp[1] = sp[1]; dp[2] = sp[2]; dp[3] = sp[3];
        }
        __syncthreads();
        bf16x8 a[4], b[4];
        for (int rb = 0; rb < 4; rb++)
            a[rb] = *reinterpret_cast<const bf16x8*>(&As[rb * 16 + m16][quad * 8]);
        for (int cb = 0; cb < 4; cb++)
            b[cb] = *reinterpret_cast<const bf16x8*>(&Bs[wave * 64 + cb * 16 + m16][quad * 8]);
        for (int rb = 0; rb < 4; rb++)
            for (int cb = 0; cb < 4; cb++)
                acc[rb][cb] = __builtin_amdgcn_mfma_f32_16x16x32_bf16(
                    a[rb], b[cb], acc[rb][cb], 0, 0, 0);
        __syncthreads();
    }

    for (int rb = 0; rb < 4; rb++) {
        for (int reg = 0; reg < 4; reg++) {
            int r = rb * 16 + quad * 4 + reg;
            int sidx = s_edge[r], didx = d_edge[r];
            for (int cb = 0; cb < 4; cb++) {
                int col = wave * 64 + cb * 16 + m16;
                float v = acc[rb][cb][reg] + bc[col]
                        + b2f(Ahb[(size_t)didx * H + col])
                        + b2f(Bhb[(size_t)sidx * H + col]);
                e_new[(size_t)(row0 + r) * H + col] = v;
            }
        }
    }
}

// ---------------------------------------------------------------- edge epilogue
// wave per edge: LN + relu + residual (in-place), sigmoid-gated scatter into agg
__global__ __launch_bounds__(256) void edge_epilogue(
    const float* __restrict__ e,
    const u16* __restrict__ Vhb,
    const int* __restrict__ ei,
    const float* __restrict__ ge, const float* __restrict__ be,
    float* __restrict__ e_io,      // in: e_new, out: e_out (in-place)
    float* __restrict__ agg)
{
    int wave = threadIdx.x >> 6, lane = threadIdx.x & 63;
    int edge = blockIdx.x * 4 + wave;
    int s = ei[edge], d = ei[E_EDGES + edge];
    size_t base = (size_t)edge * H + lane * 4;

    float4 x4 = *reinterpret_cast<const float4*>(&e_io[base]);
    float x[4] = {x4.x, x4.y, x4.z, x4.w};
    float sum = x[0] + x[1] + x[2] + x[3];
    float ss  = x[0]*x[0] + x[1]*x[1] + x[2]*x[2] + x[3]*x[3];
    for (int m = 1; m < 64; m <<= 1) {
        sum += __shfl_xor(sum, m, 64);
        ss  += __shfl_xor(ss, m, 64);
    }
    float mu  = sum * (1.0f / H);
    float var = ss * (1.0f / H) - mu * mu;
    float rs  = rsqrtf(var + LN_EPS);

    float4 e4 = *reinterpret_cast<const float4*>(&e[base]);
    float eo[4] = {e4.x, e4.y, e4.z, e4.w};
    ushort4 vh4 = *reinterpret_cast<const ushort4*>(&Vhb[(size_t)d * H + lane * 4]);
    float vh[4] = {b2f(vh4.x), b2f(vh4.y), b2f(vh4.z), b2f(vh4.w)};

    float4 out;
    float* op = &out.x;
    for (int i = 0; i < 4; i++) {
        int col = lane * 4 + i;
        float ln = (x[i] - mu) * rs * ge[col] + be[col];
        op[i] = eo[i] + fmaxf(ln, 0.f);
        float gate = 1.0f / (1.0f + __expf(-x[i]));
        atomicAdd(&agg[(size_t)s * H + col], gate * vh[i]);
    }
    *reinterpret_cast<float4*>(&e_io[base]) = out;
}

// ---------------------------------------------------------------- node epilogue
__global__ __launch_bounds__(256) void node_epilogue(
    const float* __restrict__ Uh, const float* __restrict__ agg,
    const float* __restrict__ h,
    const float* __restrict__ gh, const float* __restrict__ bh,
    float* __restrict__ h_out)
{
    int wave = threadIdx.x >> 6, lane = threadIdx.x & 63;
    int row = blockIdx.x * 4 + wave;
    size_t base = (size_t)row * H + lane * 4;

    float4 u4 = *reinterpret_cast<const float4*>(&Uh[base]);
    float4 a4 = *reinterpret_cast<const float4*>(&agg[base]);
    float x[4] = {u4.x + a4.x, u4.y + a4.y, u4.z + a4.z, u4.w + a4.w};
    float sum = x[0] + x[1] + x[2] + x[3];
    float ss  = x[0]*x[0] + x[1]*x[1] + x[2]*x[2] + x[3]*x[3];
    for (int m = 1; m < 64; m <<= 1) {
        sum += __shfl_xor(sum, m, 64);
        ss  += __shfl_xor(ss, m, 64);
    }
    float mu  = sum * (1.0f / H);
    float var = ss * (1.0f / H) - mu * mu;
    float rs  = rsqrtf(var + LN_EPS);

    float4 h4 = *reinterpret_cast<const float4*>(&h[base]);
    float hv[4] = {h4.x, h4.y, h4.z, h4.w};
    float4 out;
    float* op = &out.x;
    for (int i = 0; i < 4; i++) {
        int col = lane * 4 + i;
        float ln = (x[i] - mu) * rs * gh[col] + bh[col];
        op[i] = hv[i] + fmaxf(ln, 0.f);
    }
    *reinterpret_cast<float4*>(&h_out[base]) = out;
}

// ---------------------------------------------------------------- launch
extern "C" void kernel_launch(void* const* d_in, const int* in_sizes, int n_in,
                              void* d_out, int out_size, void* d_ws, size_t ws_size,
                              hipStream_t stream) {
    const float* h  = (const float*)d_in[0];
    const float* e  = (const float*)d_in[1];
    const int*   ei = (const int*)d_in[2];
    const float* Wu = (const float*)d_in[3];
    const float* bu = (const float*)d_in[4];
    const float* Wv = (const float*)d_in[5];
    const float* bv = (const float*)d_in[6];
    const float* Wa = (const float*)d_in[7];
    const float* ba = (const float*)d_in[8];
    const float* Wb = (const float*)d_in[9];
    const float* bb = (const float*)d_in[10];
    const float* Wc = (const float*)d_in[11];
    const float* bc = (const float*)d_in[12];
    const float* gh = (const float*)d_in[13];
    const float* bh = (const float*)d_in[14];
    const float* ge = (const float*)d_in[15];
    const float* be = (const float*)d_in[16];

    char* ws = (char*)d_ws;
    u16*   h_b = (u16*)(ws);                    // 5,120,000 B
    u16*   W4b = (u16*)(ws + 5120000);          //   524,288 B
    u16*   Wcb = (u16*)(ws + 5644288);          //   131,072 B
    float* Uh  = (float*)(ws + 5775360);        // 10,240,000 B
    u16*   Vhb = (u16*)(ws + 16015360);         // 5,120,000 B
    u16*   Ahb = (u16*)(ws + 21135360);         // 5,120,000 B
    u16*   Bhb = (u16*)(ws + 26255360);         // 5,120,000 B
    float* agg = (float*)(ws + 31375360);       // 10,240,000 B  (end: 41,615,360)

    float* h_out = (float*)d_out;
    float* e_io  = h_out + (size_t)V_NODES * H;   // e_new then e_out, in place

    convert_kernel<<<11280, 256, 0, stream>>>(h, Wu, Wv, Wa, Wb, Wc, h_b, W4b, Wcb);
    node_gemm<<<dim3(157, 4), 256, 0, stream>>>(h_b, W4b, bu, bv, ba, bb,
                                                Uh, Vhb, Ahb, Bhb, V_NODES);
    edge_gemm<<<E_EDGES / 64, 256, 0, stream>>>(e, Wcb, bc, Ahb, Bhb, ei, e_io);
    hipMemsetAsync(agg, 0, (size_t)V_NODES * H * sizeof(float), stream);
    edge_epilogue<<<E_EDGES / 4, 256, 0, stream>>>(e, Vhb, ei, ge, be, e_io, agg);
    node_epilogue<<<V_NODES / 4, 256, 0, stream>>>(Uh, agg, h, gh, bh, h_out);
}

// Round 2
// 698.913 us; speedup vs baseline: 1.5323x; 1.5323x over previous
//
#include <hip/hip_runtime.h>
#include <hip/hip_bf16.h>

#define V_NODES 10000
#define E_EDGES 160000
#define H 256
#define LN_EPS 1e-5f

using bf16x8 = __attribute__((ext_vector_type(8))) __bf16;
using f32x4  = __attribute__((ext_vector_type(4))) float;
typedef unsigned short u16;
typedef unsigned int u32;

// LDS leading-dim pad: 48 u16 = 96 B stride (16B-aligned, breaks 8-way bank aliasing)
#define APAD 48

__device__ __forceinline__ u16 f2b(float f) {
    u32 u = __float_as_uint(f);
    u32 r = u + 0x7fffu + ((u >> 16) & 1u);   // RNE
    return (u16)(r >> 16);
}
__device__ __forceinline__ float b2f(u16 h) {
    return __uint_as_float(((u32)h) << 16);
}

// ---------------------------------------------------------------- convert
__global__ __launch_bounds__(256) void convert_kernel(
    const float* __restrict__ h, const float* __restrict__ Wu,
    const float* __restrict__ Wv, const float* __restrict__ Wa,
    const float* __restrict__ Wb, const float* __restrict__ Wc,
    u16* __restrict__ h_b, u16* __restrict__ W4b, u16* __restrict__ Wcb)
{
    int i = blockIdx.x * 256 + threadIdx.x;
    const int NH = V_NODES * H;        // 2,560,000
    const int NW4 = 4 * H * H;         // 262,144
    const int NWC = H * H;             // 65,536
    if (i < NH) {
        h_b[i] = f2b(h[i]);
    } else if (i < NH + NW4) {
        int j = i - NH;
        int w = j >> 16;               // which weight matrix
        int r = j & 0xffff;            // flat index within it
        const float* W = (w == 0) ? Wu : (w == 1) ? Wv : (w == 2) ? Wa : Wb;
        W4b[j] = f2b(W[r]);
    } else if (i < NH + NW4 + NWC) {
        int j = i - NH - NW4;
        Wcb[j] = f2b(Wc[j]);
    }
}

// ---------------------------------------------------------------- CSR build
__global__ __launch_bounds__(256) void hist_kernel(
    const int* __restrict__ ei, int* __restrict__ counts)
{
    int e = blockIdx.x * 256 + threadIdx.x;
    if (e < E_EDGES) atomicAdd(&counts[ei[e]], 1);
}

// single block: exclusive scan of counts -> offsets, and cur = offsets
__global__ __launch_bounds__(256) void scan_kernel(
    const int* __restrict__ counts, int* __restrict__ offsets, int* __restrict__ cur)
{
    __shared__ int partial[256];
    int t = threadIdx.x;
    const int CHUNK = 40;              // 256*40 = 10240 >= 10000
    int lo = t * CHUNK, hi = min(lo + CHUNK, V_NODES);
    int s = 0;
    for (int i = lo; i < hi; i++) s += counts[i];
    partial[t] = s;
    __syncthreads();
    // Hillis-Steele inclusive scan
    for (int st = 1; st < 256; st <<= 1) {
        int v = (t >= st) ? partial[t - st] : 0;
        __syncthreads();
        partial[t] += v;
        __syncthreads();
    }
    int base = partial[t] - s;         // exclusive base for this chunk
    for (int i = lo; i < hi; i++) {
        offsets[i] = base;
        cur[i] = base;
        base += counts[i];
    }
}

// scatter edge ids (+ dst) into CSR order
__global__ __launch_bounds__(256) void scatter_kernel(
    const int* __restrict__ ei, int* __restrict__ cur, int2* __restrict__ pairs)
{
    int e = blockIdx.x * 256 + threadIdx.x;
    if (e < E_EDGES) {
        int s = ei[e];
        int d = ei[E_EDGES + e];
        int pos = atomicAdd(&cur[s], 1);
        pairs[pos] = make_int2(e, d);
    }
}

// ---------------------------------------------------------------- node GEMM
// out(V x 1024) = h_b(V x 256) @ W4b(1024 x 256)^T ; col blocks: Uh|Vh|Ah|Bh
__global__ __launch_bounds__(256) void node_gemm(
    const u16* __restrict__ Xb, const u16* __restrict__ Wb,
    const float* __restrict__ bu, const float* __restrict__ bv,
    const float* __restrict__ ba, const float* __restrict__ bb,
    float* __restrict__ Uh, u16* __restrict__ Vh,
    u16* __restrict__ Ah, u16* __restrict__ Bh, int M)
{
    __shared__ __align__(16) u16 As[64][APAD];
    __shared__ __align__(16) u16 Bs[256][APAD];

    int cb_blk = blockIdx.y;
    int row0 = blockIdx.x * 64;
    int tid = threadIdx.x;
    int wave = tid >> 6, lane = tid & 63;
    int quad = lane >> 4, m16 = lane & 15;

    f32x4 acc[4][4];
    for (int a = 0; a < 4; a++)
        for (int b = 0; b < 4; b++)
            acc[a][b] = f32x4{0.f, 0.f, 0.f, 0.f};

    for (int kc = 0; kc < H; kc += 32) {
        { // stage A: 64 rows x 32 k (bf16), 16B per thread
            int r = tid >> 2, seg = tid & 3;
            int gr = row0 + r; if (gr >= M) gr = M - 1;
            *reinterpret_cast<uint4*>(&As[r][seg * 8]) =
                *reinterpret_cast<const uint4*>(&Xb[(size_t)gr * H + kc + seg * 8]);
        }
        { // stage B: 256 W-rows x 32 k, 64B per thread
            const uint4* sp = reinterpret_cast<const uint4*>(
                &Wb[(size_t)(cb_blk * 256 + tid) * H + kc]);
            uint4* dp = reinterpret_cast<uint4*>(&Bs[tid][0]);
            dp[0] = sp[0]; dp[1] = sp[1]; dp[2] = sp[2]; dp[3] = sp[3];
        }
        __syncthreads();
        bf16x8 a[4], b[4];
        for (int rb = 0; rb < 4; rb++)
            a[rb] = *reinterpret_cast<const bf16x8*>(&As[rb * 16 + m16][quad * 8]);
        for (int cb = 0; cb < 4; cb++)
            b[cb] = *reinterpret_cast<const bf16x8*>(&Bs[wave * 64 + cb * 16 + m16][quad * 8]);
        for (int rb = 0; rb < 4; rb++)
            for (int cb = 0; cb < 4; cb++)
                acc[rb][cb] = __builtin_amdgcn_mfma_f32_16x16x32_bf16(
                    a[rb], b[cb], acc[rb][cb], 0, 0, 0);
        __syncthreads();
    }

    const float* bias = (cb_blk == 0) ? bu : (cb_blk == 1) ? bv : (cb_blk == 2) ? ba : bb;
    for (int rb = 0; rb < 4; rb++) {
        for (int cb = 0; cb < 4; cb++) {
            int col = wave * 64 + cb * 16 + m16;
            float bval = bias[col];
            for (int reg = 0; reg < 4; reg++) {
                int r = row0 + rb * 16 + quad * 4 + reg;
                if (r < M) {
                    float v = acc[rb][cb][reg] + bval;
                    size_t idx = (size_t)r * H + col;
                    if (cb_blk == 0)      Uh[idx] = v;
                    else if (cb_blk == 1) Vh[idx] = f2b(v);
                    else if (cb_blk == 2) Ah[idx] = f2b(v);
                    else                  Bh[idx] = f2b(v);
                }
            }
        }
    }
}

// ---------------------------------------------------------------- edge GEMM
// e_new(E x 256) = e @ Wc^T + bc + Ah[dst] + Bh[src], fp32 into d_out e-region
__global__ __launch_bounds__(256) void edge_gemm(
    const float* __restrict__ e, const u16* __restrict__ Wcb,
    const float* __restrict__ bc,
    const u16* __restrict__ Ahb, const u16* __restrict__ Bhb,
    const int* __restrict__ ei,
    float* __restrict__ e_new)
{
    __shared__ __align__(16) u16 As[64][APAD];
    __shared__ __align__(16) u16 Bs[256][APAD];
    __shared__ int s_edge[64], d_edge[64];

    int row0 = blockIdx.x * 64;
    int tid = threadIdx.x;
    int wave = tid >> 6, lane = tid & 63;
    int quad = lane >> 4, m16 = lane & 15;

    if (tid < 64) {
        s_edge[tid] = ei[row0 + tid];
        d_edge[tid] = ei[E_EDGES + row0 + tid];
    }

    f32x4 acc[4][4];
    for (int a = 0; a < 4; a++)
        for (int b = 0; b < 4; b++)
            acc[a][b] = f32x4{0.f, 0.f, 0.f, 0.f};

    for (int kc = 0; kc < H; kc += 32) {
        { // stage A: read e fp32, convert to bf16 inline
            int r = tid >> 2, seg = tid & 3;
            const float4* sp = reinterpret_cast<const float4*>(
                &e[(size_t)(row0 + r) * H + kc + seg * 8]);
            float4 f0 = sp[0], f1 = sp[1];
            ushort4 lo, hi;
            lo.x = f2b(f0.x); lo.y = f2b(f0.y); lo.z = f2b(f0.z); lo.w = f2b(f0.w);
            hi.x = f2b(f1.x); hi.y = f2b(f1.y); hi.z = f2b(f1.z); hi.w = f2b(f1.w);
            *reinterpret_cast<ushort4*>(&As[r][seg * 8])     = lo;
            *reinterpret_cast<ushort4*>(&As[r][seg * 8 + 4]) = hi;
        }
        { // stage B (Wc is 256x256)
            const uint4* sp = reinterpret_cast<const uint4*>(&Wcb[(size_t)tid * H + kc]);
            uint4* dp = reinterpret_cast<uint4*>(&Bs[tid][0]);
            dp[0] = sp[0]; dp[1] = sp[1]; dp[2] = sp[2]; dp[3] = sp[3];
        }
        __syncthreads();
        bf16x8 a[4], b[4];
        for (int rb = 0; rb < 4; rb++)
            a[rb] = *reinterpret_cast<const bf16x8*>(&As[rb * 16 + m16][quad * 8]);
        for (int cb = 0; cb < 4; cb++)
            b[cb] = *reinterpret_cast<const bf16x8*>(&Bs[wave * 64 + cb * 16 + m16][quad * 8]);
        for (int rb = 0; rb < 4; rb++)
            for (int cb = 0; cb < 4; cb++)
                acc[rb][cb] = __builtin_amdgcn_mfma_f32_16x16x32_bf16(
                    a[rb], b[cb], acc[rb][cb], 0, 0, 0);
        __syncthreads();
    }

    for (int rb = 0; rb < 4; rb++) {
        for (int reg = 0; reg < 4; reg++) {
            int r = rb * 16 + quad * 4 + reg;
            int sidx = s_edge[r], didx = d_edge[r];
            for (int cb = 0; cb < 4; cb++) {
                int col = wave * 64 + cb * 16 + m16;
                float v = acc[rb][cb][reg] + bc[col]
                        + b2f(Ahb[(size_t)didx * H + col])
                        + b2f(Bhb[(size_t)sidx * H + col]);
                e_new[(size_t)(row0 + r) * H + col] = v;
            }
        }
    }
}

// ---------------------------------------------------------------- node agg + epilogue
// wave per node: CSR gather of sigmoid(e_new)*Vh[dst], then LN+relu+residual
__global__ __launch_bounds__(256) void node_agg_epilogue(
    const float* __restrict__ Uh, const float* __restrict__ h,
    const float* __restrict__ e_new,
    const u16* __restrict__ Vhb,
    const int* __restrict__ counts, const int* __restrict__ offsets,
    const int2* __restrict__ pairs,
    const float* __restrict__ gh, const float* __restrict__ bh,
    float* __restrict__ h_out)
{
    int wave = threadIdx.x >> 6, lane = threadIdx.x & 63;
    int n = blockIdx.x * 4 + wave;
    int cnt = counts[n], off = offsets[n];

    float acc[4] = {0.f, 0.f, 0.f, 0.f};
    for (int j = 0; j < cnt; j++) {
        int2 p = pairs[off + j];
        int eid = p.x, d = p.y;
        float4 x4 = *reinterpret_cast<const float4*>(&e_new[(size_t)eid * H + lane * 4]);
        ushort4 v4 = *reinterpret_cast<const ushort4*>(&Vhb[(size_t)d * H + lane * 4]);
        float xs[4] = {x4.x, x4.y, x4.z, x4.w};
        float vs[4] = {b2f(v4.x), b2f(v4.y), b2f(v4.z), b2f(v4.w)};
        for (int i = 0; i < 4; i++)
            acc[i] += vs[i] / (1.0f + __expf(-xs[i]));
    }

    size_t base = (size_t)n * H + lane * 4;
    float4 u4 = *reinterpret_cast<const float4*>(&Uh[base]);
    float x[4] = {u4.x + acc[0], u4.y + acc[1], u4.z + acc[2], u4.w + acc[3]};
    float sum = x[0] + x[1] + x[2] + x[3];
    float ss  = x[0]*x[0] + x[1]*x[1] + x[2]*x[2] + x[3]*x[3];
    for (int m = 1; m < 64; m <<= 1) {
        sum += __shfl_xor(sum, m, 64);
        ss  += __shfl_xor(ss, m, 64);
    }
    float mu  = sum * (1.0f / H);
    float var = ss * (1.0f / H) - mu * mu;
    float rs  = rsqrtf(var + LN_EPS);

    float4 h4 = *reinterpret_cast<const float4*>(&h[base]);
    float hv[4] = {h4.x, h4.y, h4.z, h4.w};
    float4 out;
    float* op = &out.x;
    for (int i = 0; i < 4; i++) {
        int col = lane * 4 + i;
        float ln = (x[i] - mu) * rs * gh[col] + bh[col];
        op[i] = hv[i] + fmaxf(ln, 0.f);
    }
    *reinterpret_cast<float4*>(&h_out[base]) = out;
}

// ---------------------------------------------------------------- edge LN
// wave per edge: LN + relu + residual, in-place e_new -> e_out (no atomics)
__global__ __launch_bounds__(256) void edge_ln(
    const float* __restrict__ e,
    const float* __restrict__ ge, const float* __restrict__ be,
    float* __restrict__ e_io)
{
    int wave = threadIdx.x >> 6, lane = threadIdx.x & 63;
    int edge = blockIdx.x * 4 + wave;
    size_t base = (size_t)edge * H + lane * 4;

    float4 x4 = *reinterpret_cast<const float4*>(&e_io[base]);
    float x[4] = {x4.x, x4.y, x4.z, x4.w};
    float sum = x[0] + x[1] + x[2] + x[3];
    float ss  = x[0]*x[0] + x[1]*x[1] + x[2]*x[2] + x[3]*x[3];
    for (int m = 1; m < 64; m <<= 1) {
        sum += __shfl_xor(sum, m, 64);
        ss  += __shfl_xor(ss, m, 64);
    }
    float mu  = sum * (1.0f / H);
    float var = ss * (1.0f / H) - mu * mu;
    float rs  = rsqrtf(var + LN_EPS);

    float4 e4 = *reinterpret_cast<const float4*>(&e[base]);
    float eo[4] = {e4.x, e4.y, e4.z, e4.w};
    float4 out;
    float* op = &out.x;
    for (int i = 0; i < 4; i++) {
        int col = lane * 4 + i;
        float ln = (x[i] - mu) * rs * ge[col] + be[col];
        op[i] = eo[i] + fmaxf(ln, 0.f);
    }
    *reinterpret_cast<float4*>(&e_io[base]) = out;
}

// ---------------------------------------------------------------- launch
extern "C" void kernel_launch(void* const* d_in, const int* in_sizes, int n_in,
                              void* d_out, int out_size, void* d_ws, size_t ws_size,
                              hipStream_t stream) {
    const float* h  = (const float*)d_in[0];
    const float* e  = (const float*)d_in[1];
    const int*   ei = (const int*)d_in[2];
    const float* Wu = (const float*)d_in[3];
    const float* bu = (const float*)d_in[4];
    const float* Wv = (const float*)d_in[5];
    const float* bv = (const float*)d_in[6];
    const float* Wa = (const float*)d_in[7];
    const float* ba = (const float*)d_in[8];
    const float* Wb = (const float*)d_in[9];
    const float* bb = (const float*)d_in[10];
    const float* Wc = (const float*)d_in[11];
    const float* bc = (const float*)d_in[12];
    const float* gh = (const float*)d_in[13];
    const float* bh = (const float*)d_in[14];
    const float* ge = (const float*)d_in[15];
    const float* be = (const float*)d_in[16];

    char* ws = (char*)d_ws;
    u16*   h_b     = (u16*)(ws);                  // 5,120,000 B
    u16*   W4b     = (u16*)(ws + 5120000);        //   524,288 B
    u16*   Wcb     = (u16*)(ws + 5644288);        //   131,072 B
    float* Uh      = (float*)(ws + 5775360);      // 10,240,000 B
    u16*   Vhb     = (u16*)(ws + 16015360);       // 5,120,000 B
    u16*   Ahb     = (u16*)(ws + 21135360);       // 5,120,000 B
    u16*   Bhb     = (u16*)(ws + 26255360);       // 5,120,000 B
    int*   counts  = (int*)(ws + 31375360);       //    40,000 B
    int*   offsets = (int*)(ws + 31415360);       //    40,000 B
    int*   cur     = (int*)(ws + 31455360);       //    40,000 B
    int2*  pairs   = (int2*)(ws + 31495360);      // 1,280,000 B (end: 32,775,360)

    float* h_out = (float*)d_out;
    float* e_io  = h_out + (size_t)V_NODES * H;   // e_new then e_out, in place

    convert_kernel<<<11280, 256, 0, stream>>>(h, Wu, Wv, Wa, Wb, Wc, h_b, W4b, Wcb);
    hipMemsetAsync(counts, 0, V_NODES * sizeof(int), stream);
    hist_kernel<<<625, 256, 0, stream>>>(ei, counts);
    scan_kernel<<<1, 256, 0, stream>>>(counts, offsets, cur);
    scatter_kernel<<<625, 256, 0, stream>>>(ei, cur, pairs);
    node_gemm<<<dim3(157, 4), 256, 0, stream>>>(h_b, W4b, bu, bv, ba, bb,
                                                Uh, Vhb, Ahb, Bhb, V_NODES);
    edge_gemm<<<E_EDGES / 64, 256, 0, stream>>>(e, Wcb, bc, Ahb, Bhb, ei, e_io);
    node_agg_epilogue<<<V_NODES / 4, 256, 0, stream>>>(Uh, h, e_io, Vhb,
                                                       counts, offsets, pairs,
                                                       gh, bh, h_out);
    edge_ln<<<E_EDGES / 4, 256, 0, stream>>>(e, ge, be, e_io);
}